// Round 5
// baseline (195.767 us; speedup 1.0000x reference)
//
#include <hip/hip_runtime.h>
#include <hip/hip_bf16.h>

#define NB 4
#define NC 48
#define H0 512
#define W0 512
#define NCH 17   // 1 intensity + 16 mueller
#define OUTC 51  // 17 * 3 levels

// ---------------------------------------------------------------------------
// 4x4 inverse via adjugate (row-major).
// ---------------------------------------------------------------------------
__device__ __forceinline__ void inv4x4(const float* m, float* o) {
    float inv[16];
    inv[0]  =  m[5]*m[10]*m[15] - m[5]*m[11]*m[14] - m[9]*m[6]*m[15] + m[9]*m[7]*m[14] + m[13]*m[6]*m[11] - m[13]*m[7]*m[10];
    inv[4]  = -m[4]*m[10]*m[15] + m[4]*m[11]*m[14] + m[8]*m[6]*m[15] - m[8]*m[7]*m[14] - m[12]*m[6]*m[11] + m[12]*m[7]*m[10];
    inv[8]  =  m[4]*m[9]*m[15]  - m[4]*m[11]*m[13] - m[8]*m[5]*m[15] + m[8]*m[7]*m[13] + m[12]*m[5]*m[11] - m[12]*m[7]*m[9];
    inv[12] = -m[4]*m[9]*m[14]  + m[4]*m[10]*m[13] + m[8]*m[5]*m[14] - m[8]*m[6]*m[13] - m[12]*m[5]*m[10] + m[12]*m[6]*m[9];
    inv[1]  = -m[1]*m[10]*m[15] + m[1]*m[11]*m[14] + m[9]*m[2]*m[15] - m[9]*m[3]*m[14] - m[13]*m[2]*m[11] + m[13]*m[3]*m[10];
    inv[5]  =  m[0]*m[10]*m[15] - m[0]*m[11]*m[14] - m[8]*m[2]*m[15] + m[8]*m[3]*m[14] + m[12]*m[2]*m[11] - m[12]*m[3]*m[10];
    inv[9]  = -m[0]*m[9]*m[15]  + m[0]*m[11]*m[13] + m[8]*m[1]*m[15] - m[8]*m[3]*m[13] - m[12]*m[1]*m[11] + m[12]*m[3]*m[9];
    inv[13] =  m[0]*m[9]*m[14]  - m[0]*m[10]*m[13] - m[8]*m[1]*m[14] + m[8]*m[2]*m[13] + m[12]*m[1]*m[10] - m[12]*m[2]*m[9];
    inv[2]  =  m[1]*m[6]*m[15]  - m[1]*m[7]*m[14]  - m[5]*m[2]*m[15] + m[5]*m[3]*m[14] + m[13]*m[2]*m[7]  - m[13]*m[3]*m[6];
    inv[6]  = -m[0]*m[6]*m[15]  + m[0]*m[7]*m[14]  + m[4]*m[2]*m[15] - m[4]*m[3]*m[14] - m[12]*m[2]*m[7]  + m[12]*m[3]*m[6];
    inv[10] =  m[0]*m[5]*m[15]  - m[0]*m[7]*m[13]  - m[4]*m[1]*m[15] + m[4]*m[3]*m[13] + m[12]*m[1]*m[7]  - m[12]*m[3]*m[5];
    inv[14] = -m[0]*m[5]*m[14]  + m[0]*m[6]*m[13]  + m[4]*m[1]*m[14] - m[4]*m[2]*m[13] - m[12]*m[1]*m[6]  + m[12]*m[2]*m[5];
    inv[3]  = -m[1]*m[6]*m[11]  + m[1]*m[7]*m[10]  + m[5]*m[2]*m[11] - m[5]*m[3]*m[10] - m[9]*m[2]*m[7]   + m[9]*m[3]*m[6];
    inv[7]  =  m[0]*m[6]*m[11]  - m[0]*m[7]*m[10]  - m[4]*m[2]*m[11] + m[4]*m[3]*m[10] + m[8]*m[2]*m[7]   - m[8]*m[3]*m[6];
    inv[11] = -m[0]*m[5]*m[11]  + m[0]*m[7]*m[9]   + m[4]*m[1]*m[11] - m[4]*m[3]*m[9]  - m[8]*m[1]*m[7]   + m[8]*m[3]*m[5];
    inv[15] =  m[0]*m[5]*m[10]  - m[0]*m[6]*m[9]   - m[4]*m[1]*m[10] + m[4]*m[2]*m[9]  + m[8]*m[1]*m[6]   - m[8]*m[2]*m[5];
    float det = m[0]*inv[0] + m[1]*inv[4] + m[2]*inv[8] + m[3]*inv[12];
    float rd = 1.0f / det;
    #pragma unroll
    for (int i = 0; i < 16; i++) o[i] = inv[i] * rd;
}

// ---------------------------------------------------------------------------
// Fused Mueller features + optional 4x4 maxpool, register-resident.
// One block = 16x16 pixel tile. tid = ly*16+lx, so lane = (ly&3)*16+lx and a
// 4x4 pool window lives in ONE wave (butterfly masks {1,2,16,32}).
// Each thread loads its 48 channels ONCE and PINS each value in a VGPR with
// an empty inline asm ("+v") so the compiler cannot rematerialize the global
// loads (round-3 failure mode: VGPR_Count=40 -> L2 reloads in the math phase).
// ---------------------------------------------------------------------------
template <bool POOL>
__global__ __launch_bounds__(256) void fused_feat_pool_reg(
        const float* __restrict__ in, float* __restrict__ featout,
        float* __restrict__ poolout, int h, int w, int cpb) {
    int tilesX = w >> 4;
    int tilesY = h >> 4;
    int tile = blockIdx.x;
    int b = tile / (tilesX * tilesY);
    int trem = tile - b * (tilesX * tilesY);
    int tileY = trem / tilesX;
    int tileX = trem - tileY * tilesX;

    int tid = threadIdx.x;
    int ly = tid >> 4;           // 0..15
    int lx = tid & 15;           // 0..15
    int y = (tileY << 4) + ly;
    int x = (tileX << 4) + lx;
    int hw = h * w;
    size_t pix = (size_t)y * w + x;
    const float* px = in + (size_t)b * NC * hw + pix;

    // ---- load all 48 channels once; pin each in a VGPR (no remat) ----
    float v[NC];
    #pragma unroll
    for (int k = 0; k < NC; k++) {
        v[k] = px[(size_t)k * hw];
        asm volatile("" : "+v"(v[k]));   // keep-alive: forbid rematerialization
    }

    // ---- maxpool: 4x4 window reduction inside the wave ----
    if (POOL) {
        int ho = h >> 2, wo = w >> 2;
        int py = (tileY << 2) + (ly >> 2);
        int px2 = (tileX << 2) + (lx >> 2);
        bool writer = ((lx & 3) == 0) && ((ly & 3) == 0);
        #pragma unroll
        for (int k = 0; k < NC; k++) {
            float m = v[k];
            m = fmaxf(m, __shfl_xor(m, 1));
            m = fmaxf(m, __shfl_xor(m, 2));
            m = fmaxf(m, __shfl_xor(m, 16));
            m = fmaxf(m, __shfl_xor(m, 32));
            if (writer)
                poolout[((size_t)(b * NC + k) * ho + py) * wo + px2] = m;
        }
    }

    // ---- Mueller features ----
    float iA[16], iW[16];
    inv4x4(v + 16, iA);
    inv4x4(v + 32, iW);

    float T[16];
    float inten = 0.f;
    #pragma unroll
    for (int c = 0; c < 4; c++) {
        float i0 = v[0 + c], i1 = v[4 + c], i2 = v[8 + c], i3 = v[12 + c];
        inten += i0 + i1 + i2 + i3;
        #pragma unroll
        for (int r = 0; r < 4; r++)
            T[r * 4 + c] = iA[r * 4 + 0] * i0 + iA[r * 4 + 1] * i1 +
                           iA[r * 4 + 2] * i2 + iA[r * 4 + 3] * i3;
    }
    inten *= (1.0f / 16.0f);

    float M[16];
    #pragma unroll
    for (int r = 0; r < 4; r++)
        #pragma unroll
        for (int c = 0; c < 4; c++)
            M[r * 4 + c] = T[r * 4 + 0] * iW[0 * 4 + c] + T[r * 4 + 1] * iW[1 * 4 + c] +
                           T[r * 4 + 2] * iW[2 * 4 + c] + T[r * 4 + 3] * iW[3 * 4 + c];
    float rm = 1.0f / M[0];

    float* op = featout + (size_t)b * cpb * hw + pix;
    op[0] = inten;
    #pragma unroll
    for (int k = 0; k < 16; k++) op[(size_t)(k + 1) * hw] = M[k] * rm;
}

// ---------------------------------------------------------------------------
// Plain per-pixel features (no pool) for the tiny 32x32 level.
// ---------------------------------------------------------------------------
__global__ __launch_bounds__(256) void feat_kernel(
        const float* __restrict__ in, float* __restrict__ out, int h, int w) {
    int hw = h * w;
    int npix = NB * hw;
    int idx = blockIdx.x * blockDim.x + threadIdx.x;
    if (idx >= npix) return;
    int b = idx / hw;
    int p = idx - b * hw;
    const float* px = in + (size_t)b * NC * hw + p;

    float Iv[16], tmp[16], iA[16], iW[16];
    #pragma unroll
    for (int k = 0; k < 16; k++) Iv[k] = px[(size_t)k * hw];
    #pragma unroll
    for (int k = 0; k < 16; k++) tmp[k] = px[(size_t)(16 + k) * hw];
    inv4x4(tmp, iA);
    #pragma unroll
    for (int k = 0; k < 16; k++) tmp[k] = px[(size_t)(32 + k) * hw];
    inv4x4(tmp, iW);

    float T[16];
    #pragma unroll
    for (int r = 0; r < 4; r++)
        #pragma unroll
        for (int c = 0; c < 4; c++)
            T[r * 4 + c] = iA[r * 4 + 0] * Iv[0 + c] + iA[r * 4 + 1] * Iv[4 + c] +
                           iA[r * 4 + 2] * Iv[8 + c] + iA[r * 4 + 3] * Iv[12 + c];
    float M[16];
    #pragma unroll
    for (int r = 0; r < 4; r++)
        #pragma unroll
        for (int c = 0; c < 4; c++)
            M[r * 4 + c] = T[r * 4 + 0] * iW[0 * 4 + c] + T[r * 4 + 1] * iW[1 * 4 + c] +
                           T[r * 4 + 2] * iW[2 * 4 + c] + T[r * 4 + 3] * iW[3 * 4 + c];
    float rm = 1.0f / M[0];

    float inten = 0.f;
    #pragma unroll
    for (int k = 0; k < 16; k++) inten += Iv[k];
    inten *= (1.0f / 16.0f);

    float* op = out + (size_t)b * NCH * hw + p;
    op[0] = inten;
    #pragma unroll
    for (int k = 0; k < 16; k++) op[(size_t)(k + 1) * hw] = M[k] * rm;
}

// ---------------------------------------------------------------------------
// Bilinear upsample (align_corners=True) of BOTH pyramid levels to 512x512.
// ---------------------------------------------------------------------------
__global__ __launch_bounds__(256) void upsample_both_kernel(
        const float* __restrict__ feat1, const float* __restrict__ feat2,
        float* __restrict__ out) {
    int idx = blockIdx.x * blockDim.x + threadIdx.x;
    int total = NB * H0 * W0;
    if (idx >= total) return;
    int X = idx % W0;
    int Y = (idx / W0) % H0;
    int b = idx / (W0 * H0);

    const float* feats[2] = {feat1, feat2};
    const int dims[2] = {128, 32};
    const int choffs[2] = {17, 34};

    #pragma unroll
    for (int l = 0; l < 2; l++) {
        int h = dims[l], w = dims[l];
        float sy = (float)(h - 1) / (float)(H0 - 1);
        float sx = (float)(w - 1) / (float)(W0 - 1);
        float yf = (float)Y * sy;
        float xf = (float)X * sx;
        int y0 = (int)yf;
        int x0 = (int)xf;
        if (y0 > h - 1) y0 = h - 1;
        if (x0 > w - 1) x0 = w - 1;
        int y1 = min(y0 + 1, h - 1);
        int x1 = min(x0 + 1, w - 1);
        float fy = yf - (float)y0;
        float fx = xf - (float)x0;

        const float* fb = feats[l] + (size_t)b * NCH * h * w;
        float* ob = out + ((size_t)b * OUTC + choffs[l]) * (size_t)(H0 * W0) + (size_t)Y * W0 + X;
        for (int c = 0; c < NCH; c++) {
            const float* fc = fb + (size_t)c * h * w;
            float v00 = fc[(size_t)y0 * w + x0];
            float v01 = fc[(size_t)y0 * w + x1];
            float v10 = fc[(size_t)y1 * w + x0];
            float v11 = fc[(size_t)y1 * w + x1];
            float a  = v00 * (1.f - fy) + v10 * fy;
            float bb = v01 * (1.f - fy) + v11 * fy;
            ob[(size_t)c * (H0 * W0)] = a * (1.f - fx) + bb * fx;
        }
    }
}

extern "C" void kernel_launch(void* const* d_in, const int* in_sizes, int n_in,
                              void* d_out, int out_size, void* d_ws, size_t ws_size,
                              hipStream_t stream) {
    const float* x = (const float*)d_in[0];
    float* out = (float*)d_out;
    float* ws = (float*)d_ws;

    // workspace layout (floats)
    float* pool1 = ws;                                            // 4*48*128*128
    float* pool2 = pool1 + (size_t)NB * NC * 128 * 128;           // 4*48*32*32
    float* feat1 = pool2 + (size_t)NB * NC * 32 * 32;             // 4*17*128*128
    float* feat2 = feat1 + (size_t)NB * NCH * 128 * 128;          // 4*17*32*32

    // level 0: features -> out ch 0..16 (cpb=51), pool -> pool1. x read once.
    {
        int blocks = NB * (512 / 16) * (512 / 16);   // 4096
        fused_feat_pool_reg<true><<<blocks, 256, 0, stream>>>(x, out, pool1, 512, 512, OUTC);
    }
    // level 1: features -> feat1 (cpb=17), pool -> pool2
    {
        int blocks = NB * (128 / 16) * (128 / 16);   // 256
        fused_feat_pool_reg<true><<<blocks, 256, 0, stream>>>(pool1, feat1, pool2, 128, 128, NCH);
    }
    // level 2: features only -> feat2
    {
        int t = NB * 32 * 32;
        feat_kernel<<<(t + 255) / 256, 256, 0, stream>>>(pool2, feat2, 32, 32);
    }
    // upsample both levels -> out ch 17..50
    {
        int t = NB * H0 * W0;
        upsample_both_kernel<<<(t + 255) / 256, 256, 0, stream>>>(feat1, feat2, out);
    }
}

// Round 6
// 164.897 us; speedup vs baseline: 1.1872x; 1.1872x over previous
//
#include <hip/hip_runtime.h>
#include <hip/hip_bf16.h>

#define NB 4
#define NC 48
#define H0 512
#define W0 512
#define NCH 17   // 1 intensity + 16 mueller
#define OUTC 51  // 17 * 3 levels

// ---------------------------------------------------------------------------
// 4x4 inverse via adjugate (row-major).
// ---------------------------------------------------------------------------
__device__ __forceinline__ void inv4x4(const float* m, float* o) {
    float inv[16];
    inv[0]  =  m[5]*m[10]*m[15] - m[5]*m[11]*m[14] - m[9]*m[6]*m[15] + m[9]*m[7]*m[14] + m[13]*m[6]*m[11] - m[13]*m[7]*m[10];
    inv[4]  = -m[4]*m[10]*m[15] + m[4]*m[11]*m[14] + m[8]*m[6]*m[15] - m[8]*m[7]*m[14] - m[12]*m[6]*m[11] + m[12]*m[7]*m[10];
    inv[8]  =  m[4]*m[9]*m[15]  - m[4]*m[11]*m[13] - m[8]*m[5]*m[15] + m[8]*m[7]*m[13] + m[12]*m[5]*m[11] - m[12]*m[7]*m[9];
    inv[12] = -m[4]*m[9]*m[14]  + m[4]*m[10]*m[13] + m[8]*m[5]*m[14] - m[8]*m[6]*m[13] - m[12]*m[5]*m[10] + m[12]*m[6]*m[9];
    inv[1]  = -m[1]*m[10]*m[15] + m[1]*m[11]*m[14] + m[9]*m[2]*m[15] - m[9]*m[3]*m[14] - m[13]*m[2]*m[11] + m[13]*m[3]*m[10];
    inv[5]  =  m[0]*m[10]*m[15] - m[0]*m[11]*m[14] - m[8]*m[2]*m[15] + m[8]*m[3]*m[14] + m[12]*m[2]*m[11] - m[12]*m[3]*m[10];
    inv[9]  = -m[0]*m[9]*m[15]  + m[0]*m[11]*m[13] + m[8]*m[1]*m[15] - m[8]*m[3]*m[13] - m[12]*m[1]*m[11] + m[12]*m[3]*m[9];
    inv[13] =  m[0]*m[9]*m[14]  - m[0]*m[10]*m[13] - m[8]*m[1]*m[14] + m[8]*m[2]*m[13] + m[12]*m[1]*m[10] - m[12]*m[2]*m[9];
    inv[2]  =  m[1]*m[6]*m[15]  - m[1]*m[7]*m[14]  - m[5]*m[2]*m[15] + m[5]*m[3]*m[14] + m[13]*m[2]*m[7]  - m[13]*m[3]*m[6];
    inv[6]  = -m[0]*m[6]*m[15]  + m[0]*m[7]*m[14]  + m[4]*m[2]*m[15] - m[4]*m[3]*m[14] - m[12]*m[2]*m[7]  + m[12]*m[3]*m[6];
    inv[10] =  m[0]*m[5]*m[15]  - m[0]*m[7]*m[13]  - m[4]*m[1]*m[15] + m[4]*m[3]*m[13] + m[12]*m[1]*m[7]  - m[12]*m[3]*m[5];
    inv[14] = -m[0]*m[5]*m[14]  + m[0]*m[6]*m[13]  + m[4]*m[1]*m[14] - m[4]*m[2]*m[13] - m[12]*m[1]*m[6]  + m[12]*m[2]*m[5];
    inv[3]  = -m[1]*m[6]*m[11]  + m[1]*m[7]*m[10]  + m[5]*m[2]*m[11] - m[5]*m[3]*m[10] - m[9]*m[2]*m[7]   + m[9]*m[3]*m[6];
    inv[7]  =  m[0]*m[6]*m[11]  - m[0]*m[7]*m[10]  - m[4]*m[2]*m[11] + m[4]*m[3]*m[10] + m[8]*m[2]*m[7]   - m[8]*m[3]*m[6];
    inv[11] = -m[0]*m[5]*m[11]  + m[0]*m[7]*m[9]   + m[4]*m[1]*m[11] - m[4]*m[3]*m[9]  - m[8]*m[1]*m[7]   + m[8]*m[3]*m[5];
    inv[15] =  m[0]*m[5]*m[10]  - m[0]*m[6]*m[9]   - m[4]*m[1]*m[10] + m[4]*m[2]*m[9]  + m[8]*m[1]*m[6]   - m[8]*m[2]*m[5];
    float det = m[0]*inv[0] + m[1]*inv[4] + m[2]*inv[8] + m[3]*inv[12];
    float rd = 1.0f / det;
    #pragma unroll
    for (int i = 0; i < 16; i++) o[i] = inv[i] * rd;
}

// ---------------------------------------------------------------------------
// Fused Mueller features + 4x4 maxpool, register-resident.
// One block = 16x16 pixel tile. tid = ly*16+lx, lane = (ly&3)*16+lx -> a 4x4
// pool window lives in ONE wave (butterfly masks {1,2,16,32}).
//
// ANTI-REMAT CONTRACT: pointers are deliberately NOT const / NOT __restrict__.
// The pool-phase stores may alias `in` as far as the compiler can prove, so
// all 48 channel loads MUST be issued before the first pool store and can
// never be re-issued (rematerialized) after it -> the channel set stays in
// VGPRs across pool + math. launch_bounds(256,4) grants a 128-VGPR budget
// (4 waves/SIMD). Round-3/5 failure mode was VGPR_Count=40 + L2 reloads.
//
// Math is staged so I dies streaming:  P = I*iW,  M = iA*P  (== iA*I*iW).
// ---------------------------------------------------------------------------
__global__ __launch_bounds__(256, 4) void fused_feat_pool_reg(
        float* in, float* featout, float* poolout, int h, int w, int cpb) {
    int tilesX = w >> 4;
    int tilesY = h >> 4;
    int tile = blockIdx.x;
    int b = tile / (tilesX * tilesY);
    int trem = tile - b * (tilesX * tilesY);
    int tileY = trem / tilesX;
    int tileX = trem - tileY * tilesX;

    int tid = threadIdx.x;
    int ly = tid >> 4;           // 0..15
    int lx = tid & 15;           // 0..15
    int y = (tileY << 4) + ly;
    int x = (tileX << 4) + lx;
    int hw = h * w;
    size_t pix = (size_t)y * w + x;
    float* px = in + (size_t)b * NC * hw + pix;

    // ---- load all 48 channels once (issued before any store; no remat) ----
    float v[NC];
    #pragma unroll
    for (int k = 0; k < NC; k++) v[k] = px[(size_t)k * hw];

    // ---- maxpool: 4x4 window reduction inside the wave ----
    {
        int ho = h >> 2, wo = w >> 2;
        int py = (tileY << 2) + (ly >> 2);
        int px2 = (tileX << 2) + (lx >> 2);
        bool writer = ((lx & 3) == 0) && ((ly & 3) == 0);
        #pragma unroll
        for (int k = 0; k < NC; k++) {
            float m = v[k];
            m = fmaxf(m, __shfl_xor(m, 1));
            m = fmaxf(m, __shfl_xor(m, 2));
            m = fmaxf(m, __shfl_xor(m, 16));
            m = fmaxf(m, __shfl_xor(m, 32));
            if (writer)
                poolout[((size_t)(b * NC + k) * ho + py) * wo + px2] = m;
        }
    }

    // ---- Mueller features: iA, iW, then P = I*iW (I streams out), M = iA*P ----
    float iA[16], iW[16];
    inv4x4(v + 16, iA);   // A dies here
    inv4x4(v + 32, iW);   // W dies here

    float P[16];
    float inten = 0.f;
    #pragma unroll
    for (int r = 0; r < 4; r++) {
        float i0 = v[r * 4 + 0], i1 = v[r * 4 + 1], i2 = v[r * 4 + 2], i3 = v[r * 4 + 3];
        inten += i0 + i1 + i2 + i3;
        #pragma unroll
        for (int c = 0; c < 4; c++)
            P[r * 4 + c] = i0 * iW[0 * 4 + c] + i1 * iW[1 * 4 + c] +
                           i2 * iW[2 * 4 + c] + i3 * iW[3 * 4 + c];
    }
    inten *= (1.0f / 16.0f);

    float M[16];
    #pragma unroll
    for (int r = 0; r < 4; r++)
        #pragma unroll
        for (int c = 0; c < 4; c++)
            M[r * 4 + c] = iA[r * 4 + 0] * P[0 * 4 + c] + iA[r * 4 + 1] * P[1 * 4 + c] +
                           iA[r * 4 + 2] * P[2 * 4 + c] + iA[r * 4 + 3] * P[3 * 4 + c];
    float rm = 1.0f / M[0];

    float* op = featout + (size_t)b * cpb * hw + pix;
    op[0] = inten;
    #pragma unroll
    for (int k = 0; k < 16; k++) op[(size_t)(k + 1) * hw] = M[k] * rm;
}

// ---------------------------------------------------------------------------
// Plain per-pixel features (no pool) for the tiny 32x32 level.
// ---------------------------------------------------------------------------
__global__ __launch_bounds__(256) void feat_kernel(
        const float* __restrict__ in, float* __restrict__ out, int h, int w) {
    int hw = h * w;
    int npix = NB * hw;
    int idx = blockIdx.x * blockDim.x + threadIdx.x;
    if (idx >= npix) return;
    int b = idx / hw;
    int p = idx - b * hw;
    const float* px = in + (size_t)b * NC * hw + p;

    float Iv[16], tmp[16], iA[16], iW[16];
    #pragma unroll
    for (int k = 0; k < 16; k++) Iv[k] = px[(size_t)k * hw];
    #pragma unroll
    for (int k = 0; k < 16; k++) tmp[k] = px[(size_t)(16 + k) * hw];
    inv4x4(tmp, iA);
    #pragma unroll
    for (int k = 0; k < 16; k++) tmp[k] = px[(size_t)(32 + k) * hw];
    inv4x4(tmp, iW);

    float P[16];
    float inten = 0.f;
    #pragma unroll
    for (int r = 0; r < 4; r++) {
        float i0 = Iv[r * 4 + 0], i1 = Iv[r * 4 + 1], i2 = Iv[r * 4 + 2], i3 = Iv[r * 4 + 3];
        inten += i0 + i1 + i2 + i3;
        #pragma unroll
        for (int c = 0; c < 4; c++)
            P[r * 4 + c] = i0 * iW[0 * 4 + c] + i1 * iW[1 * 4 + c] +
                           i2 * iW[2 * 4 + c] + i3 * iW[3 * 4 + c];
    }
    inten *= (1.0f / 16.0f);

    float M[16];
    #pragma unroll
    for (int r = 0; r < 4; r++)
        #pragma unroll
        for (int c = 0; c < 4; c++)
            M[r * 4 + c] = iA[r * 4 + 0] * P[0 * 4 + c] + iA[r * 4 + 1] * P[1 * 4 + c] +
                           iA[r * 4 + 2] * P[2 * 4 + c] + iA[r * 4 + 3] * P[3 * 4 + c];
    float rm = 1.0f / M[0];

    float* op = out + (size_t)b * NCH * hw + p;
    op[0] = inten;
    #pragma unroll
    for (int k = 0; k < 16; k++) op[(size_t)(k + 1) * hw] = M[k] * rm;
}

// ---------------------------------------------------------------------------
// Bilinear upsample (align_corners=True) of BOTH pyramid levels to 512x512.
// ---------------------------------------------------------------------------
__global__ __launch_bounds__(256) void upsample_both_kernel(
        const float* __restrict__ feat1, const float* __restrict__ feat2,
        float* __restrict__ out) {
    int idx = blockIdx.x * blockDim.x + threadIdx.x;
    int total = NB * H0 * W0;
    if (idx >= total) return;
    int X = idx % W0;
    int Y = (idx / W0) % H0;
    int b = idx / (W0 * H0);

    const float* feats[2] = {feat1, feat2};
    const int dims[2] = {128, 32};
    const int choffs[2] = {17, 34};

    #pragma unroll
    for (int l = 0; l < 2; l++) {
        int h = dims[l], w = dims[l];
        float sy = (float)(h - 1) / (float)(H0 - 1);
        float sx = (float)(w - 1) / (float)(W0 - 1);
        float yf = (float)Y * sy;
        float xf = (float)X * sx;
        int y0 = (int)yf;
        int x0 = (int)xf;
        if (y0 > h - 1) y0 = h - 1;
        if (x0 > w - 1) x0 = w - 1;
        int y1 = min(y0 + 1, h - 1);
        int x1 = min(x0 + 1, w - 1);
        float fy = yf - (float)y0;
        float fx = xf - (float)x0;

        const float* fb = feats[l] + (size_t)b * NCH * h * w;
        float* ob = out + ((size_t)b * OUTC + choffs[l]) * (size_t)(H0 * W0) + (size_t)Y * W0 + X;
        for (int c = 0; c < NCH; c++) {
            const float* fc = fb + (size_t)c * h * w;
            float v00 = fc[(size_t)y0 * w + x0];
            float v01 = fc[(size_t)y0 * w + x1];
            float v10 = fc[(size_t)y1 * w + x0];
            float v11 = fc[(size_t)y1 * w + x1];
            float a  = v00 * (1.f - fy) + v10 * fy;
            float bb = v01 * (1.f - fy) + v11 * fy;
            ob[(size_t)c * (H0 * W0)] = a * (1.f - fx) + bb * fx;
        }
    }
}

extern "C" void kernel_launch(void* const* d_in, const int* in_sizes, int n_in,
                              void* d_out, int out_size, void* d_ws, size_t ws_size,
                              hipStream_t stream) {
    float* x = (float*)d_in[0];          // never written; non-const for anti-remat aliasing
    float* out = (float*)d_out;
    float* ws = (float*)d_ws;

    // workspace layout (floats)
    float* pool1 = ws;                                            // 4*48*128*128
    float* pool2 = pool1 + (size_t)NB * NC * 128 * 128;           // 4*48*32*32
    float* feat1 = pool2 + (size_t)NB * NC * 32 * 32;             // 4*17*128*128
    float* feat2 = feat1 + (size_t)NB * NCH * 128 * 128;          // 4*17*32*32

    // level 0: features -> out ch 0..16 (cpb=51), pool -> pool1. x read once.
    {
        int blocks = NB * (512 / 16) * (512 / 16);   // 4096
        fused_feat_pool_reg<<<blocks, 256, 0, stream>>>(x, out, pool1, 512, 512, OUTC);
    }
    // level 1: features -> feat1 (cpb=17), pool -> pool2
    {
        int blocks = NB * (128 / 16) * (128 / 16);   // 256
        fused_feat_pool_reg<<<blocks, 256, 0, stream>>>(pool1, feat1, pool2, 128, 128, NCH);
    }
    // level 2: features only -> feat2
    {
        int t = NB * 32 * 32;
        feat_kernel<<<(t + 255) / 256, 256, 0, stream>>>(pool2, feat2, 32, 32);
    }
    // upsample both levels -> out ch 17..50
    {
        int t = NB * H0 * W0;
        upsample_both_kernel<<<(t + 255) / 256, 256, 0, stream>>>(feat1, feat2, out);
    }
}

// Round 7
// 114.391 us; speedup vs baseline: 1.7114x; 1.4415x over previous
//
#include <hip/hip_runtime.h>
#include <hip/hip_bf16.h>

#define NB 4
#define NC 48
#define H0 512
#define W0 512
#define NCH 17   // 1 intensity + 16 mueller
#define OUTC 51  // 17 * 3 levels
#define TW 64    // tile width  (one wave row = 256B coalesced)
#define TH 4     // tile height (= pool window height)
#define SROW (TW * TH + 1)  // LDS row stride in floats (pad -> conflict-free)

typedef const float __attribute__((address_space(1))) f32g;
typedef float __attribute__((address_space(3))) f32l;

// ---------------------------------------------------------------------------
// 4x4 inverse via adjugate (row-major).
// ---------------------------------------------------------------------------
__device__ __forceinline__ void inv4x4(const float* m, float* o) {
    float inv[16];
    inv[0]  =  m[5]*m[10]*m[15] - m[5]*m[11]*m[14] - m[9]*m[6]*m[15] + m[9]*m[7]*m[14] + m[13]*m[6]*m[11] - m[13]*m[7]*m[10];
    inv[4]  = -m[4]*m[10]*m[15] + m[4]*m[11]*m[14] + m[8]*m[6]*m[15] - m[8]*m[7]*m[14] - m[12]*m[6]*m[11] + m[12]*m[7]*m[10];
    inv[8]  =  m[4]*m[9]*m[15]  - m[4]*m[11]*m[13] - m[8]*m[5]*m[15] + m[8]*m[7]*m[13] + m[12]*m[5]*m[11] - m[12]*m[7]*m[9];
    inv[12] = -m[4]*m[9]*m[14]  + m[4]*m[10]*m[13] + m[8]*m[5]*m[14] - m[8]*m[6]*m[13] - m[12]*m[5]*m[10] + m[12]*m[6]*m[9];
    inv[1]  = -m[1]*m[10]*m[15] + m[1]*m[11]*m[14] + m[9]*m[2]*m[15] - m[9]*m[3]*m[14] - m[13]*m[2]*m[11] + m[13]*m[3]*m[10];
    inv[5]  =  m[0]*m[10]*m[15] - m[0]*m[11]*m[14] - m[8]*m[2]*m[15] + m[8]*m[3]*m[14] + m[12]*m[2]*m[11] - m[12]*m[3]*m[10];
    inv[9]  = -m[0]*m[9]*m[15]  + m[0]*m[11]*m[13] + m[8]*m[1]*m[15] - m[8]*m[3]*m[13] - m[12]*m[1]*m[11] + m[12]*m[3]*m[9];
    inv[13] =  m[0]*m[9]*m[14]  - m[0]*m[10]*m[13] - m[8]*m[1]*m[14] + m[8]*m[2]*m[13] + m[12]*m[1]*m[10] - m[12]*m[2]*m[9];
    inv[2]  =  m[1]*m[6]*m[15]  - m[1]*m[7]*m[14]  - m[5]*m[2]*m[15] + m[5]*m[3]*m[14] + m[13]*m[2]*m[7]  - m[13]*m[3]*m[6];
    inv[6]  = -m[0]*m[6]*m[15]  + m[0]*m[7]*m[14]  + m[4]*m[2]*m[15] - m[4]*m[3]*m[14] - m[12]*m[2]*m[7]  + m[12]*m[3]*m[6];
    inv[10] =  m[0]*m[5]*m[15]  - m[0]*m[7]*m[13]  - m[4]*m[1]*m[15] + m[4]*m[3]*m[13] + m[12]*m[1]*m[7]  - m[12]*m[3]*m[5];
    inv[14] = -m[0]*m[5]*m[14]  + m[0]*m[6]*m[13]  + m[4]*m[1]*m[14] - m[4]*m[2]*m[13] - m[12]*m[1]*m[6]  + m[12]*m[2]*m[5];
    inv[3]  = -m[1]*m[6]*m[11]  + m[1]*m[7]*m[10]  + m[5]*m[2]*m[11] - m[5]*m[3]*m[10] - m[9]*m[2]*m[7]   + m[9]*m[3]*m[6];
    inv[7]  =  m[0]*m[6]*m[11]  - m[0]*m[7]*m[10]  - m[4]*m[2]*m[11] + m[4]*m[3]*m[10] + m[8]*m[2]*m[7]   - m[8]*m[3]*m[6];
    inv[11] = -m[0]*m[5]*m[11]  + m[0]*m[7]*m[9]   + m[4]*m[1]*m[11] - m[4]*m[3]*m[9]  - m[8]*m[1]*m[7]   + m[8]*m[3]*m[5];
    inv[15] =  m[0]*m[5]*m[10]  - m[0]*m[6]*m[9]   - m[4]*m[1]*m[10] + m[4]*m[2]*m[9]  + m[8]*m[1]*m[6]   - m[8]*m[2]*m[5];
    float det = m[0]*inv[0] + m[1]*inv[4] + m[2]*inv[8] + m[3]*inv[12];
    float rd = 1.0f / det;
    #pragma unroll
    for (int i = 0; i < 16; i++) o[i] = inv[i] * rd;
}

// ---------------------------------------------------------------------------
// Fused Mueller features + optional 4x4 maxpool, LDS-staged via async DMA.
// Block = 256 threads covering a TH x TW (4 x 64) pixel tile of one image.
// ly = tid>>6 (row = wave id), lx = tid&63 -> per-channel, per-wave loads are
// 256B contiguous. Staging uses global_load_lds (HBM->LDS DMA, no VGPR
// round-trip): each wave issues 48 async copies, one vmcnt drain at the
// barrier. LDS dest per lane = &s[k][tid] = wave-uniform base + lane*4,
// exactly the HW contract (row pad only shifts per-channel bases).
// ---------------------------------------------------------------------------
template <bool POOL>
__global__ __launch_bounds__(256) void feat_pool_lds(
        const float* __restrict__ in, float* __restrict__ featout,
        float* __restrict__ poolout, int h, int w, int cpb) {
    __shared__ float s[NC][SROW];

    int tilesX = w / TW;
    int tilesY = h / TH;
    int tile = blockIdx.x;
    int b = tile / (tilesX * tilesY);
    int trem = tile - b * (tilesX * tilesY);
    int tileY = trem / tilesX;
    int tileX = trem - tileY * tilesX;

    int tid = threadIdx.x;
    int ly = tid >> 6;          // 0..3
    int lx = tid & 63;          // 0..63
    int y = tileY * TH + ly;
    int x = tileX * TW + lx;
    int hw = h * w;
    size_t pix = (size_t)y * w + x;
    const float* px = in + (size_t)b * NC * hw + pix;

    // ---- stage all 48 channels into LDS via direct HBM->LDS DMA ----
    #pragma unroll
    for (int k = 0; k < NC; k++) {
        __builtin_amdgcn_global_load_lds((f32g*)(px + (size_t)k * hw),
                                         (f32l*)&s[k][tid], 4, 0, 0);
    }
    __syncthreads();   // drains vmcnt -> all DMA writes visible

    // ---- maxpool: tile is exactly one pool row (TH=4) x 16 pool cols ----
    if (POOL) {
        int ho = h >> 2, wo = w >> 2;
        #pragma unroll
        for (int o = tid; o < NC * 16; o += 256) {   // 768 outputs, 3/thread
            int k = o >> 4;
            int c = o & 15;
            float m = -INFINITY;
            #pragma unroll
            for (int r = 0; r < TH; r++)
                #pragma unroll
                for (int j = 0; j < 4; j++)
                    m = fmaxf(m, s[k][r * TW + c * 4 + j]);
            poolout[((size_t)(b * NC + k) * ho + tileY) * wo + tileX * 16 + c] = m;
        }
    }

    // ---- Mueller features (staged to keep VGPR peak low) ----
    float tmp[16], iA[16], iW[16];
    #pragma unroll
    for (int k = 0; k < 16; k++) tmp[k] = s[16 + k][tid];   // A
    inv4x4(tmp, iA);
    #pragma unroll
    for (int k = 0; k < 16; k++) tmp[k] = s[32 + k][tid];   // W
    inv4x4(tmp, iW);

    // T = iA * I, reading I from LDS; accumulate intensity on the fly
    float T[16];
    float inten = 0.f;
    #pragma unroll
    for (int c = 0; c < 4; c++) {
        float i0 = s[0 + c][tid], i1 = s[4 + c][tid],
              i2 = s[8 + c][tid], i3 = s[12 + c][tid];
        inten += i0 + i1 + i2 + i3;
        #pragma unroll
        for (int r = 0; r < 4; r++)
            T[r * 4 + c] = iA[r * 4 + 0] * i0 + iA[r * 4 + 1] * i1 +
                           iA[r * 4 + 2] * i2 + iA[r * 4 + 3] * i3;
    }
    inten *= (1.0f / 16.0f);

    // M = T * iW
    float M[16];
    #pragma unroll
    for (int r = 0; r < 4; r++)
        #pragma unroll
        for (int c = 0; c < 4; c++)
            M[r * 4 + c] = T[r * 4 + 0] * iW[0 * 4 + c] + T[r * 4 + 1] * iW[1 * 4 + c] +
                           T[r * 4 + 2] * iW[2 * 4 + c] + T[r * 4 + 3] * iW[3 * 4 + c];
    float rm = 1.0f / M[0];

    float* op = featout + (size_t)b * cpb * hw + pix;
    op[0] = inten;
    #pragma unroll
    for (int k = 0; k < 16; k++) op[(size_t)(k + 1) * hw] = M[k] * rm;
}

// ---------------------------------------------------------------------------
// Plain per-pixel features (no pool) for the tiny 32x32 level.
// ---------------------------------------------------------------------------
__global__ __launch_bounds__(256) void feat_kernel(
        const float* __restrict__ in, float* __restrict__ out, int h, int w) {
    int hw = h * w;
    int npix = NB * hw;
    int idx = blockIdx.x * blockDim.x + threadIdx.x;
    if (idx >= npix) return;
    int b = idx / hw;
    int p = idx - b * hw;
    const float* px = in + (size_t)b * NC * hw + p;

    float Iv[16], tmp[16], iA[16], iW[16];
    #pragma unroll
    for (int k = 0; k < 16; k++) Iv[k] = px[(size_t)k * hw];
    #pragma unroll
    for (int k = 0; k < 16; k++) tmp[k] = px[(size_t)(16 + k) * hw];
    inv4x4(tmp, iA);
    #pragma unroll
    for (int k = 0; k < 16; k++) tmp[k] = px[(size_t)(32 + k) * hw];
    inv4x4(tmp, iW);

    float T[16];
    #pragma unroll
    for (int r = 0; r < 4; r++)
        #pragma unroll
        for (int c = 0; c < 4; c++)
            T[r * 4 + c] = iA[r * 4 + 0] * Iv[0 + c] + iA[r * 4 + 1] * Iv[4 + c] +
                           iA[r * 4 + 2] * Iv[8 + c] + iA[r * 4 + 3] * Iv[12 + c];
    float M[16];
    #pragma unroll
    for (int r = 0; r < 4; r++)
        #pragma unroll
        for (int c = 0; c < 4; c++)
            M[r * 4 + c] = T[r * 4 + 0] * iW[0 * 4 + c] + T[r * 4 + 1] * iW[1 * 4 + c] +
                           T[r * 4 + 2] * iW[2 * 4 + c] + T[r * 4 + 3] * iW[3 * 4 + c];
    float rm = 1.0f / M[0];

    float inten = 0.f;
    #pragma unroll
    for (int k = 0; k < 16; k++) inten += Iv[k];
    inten *= (1.0f / 16.0f);

    float* op = out + (size_t)b * NCH * hw + p;
    op[0] = inten;
    #pragma unroll
    for (int k = 0; k < 16; k++) op[(size_t)(k + 1) * hw] = M[k] * rm;
}

// ---------------------------------------------------------------------------
// Bilinear upsample (align_corners=True) of BOTH pyramid levels to 512x512.
// ---------------------------------------------------------------------------
__global__ __launch_bounds__(256) void upsample_both_kernel(
        const float* __restrict__ feat1, const float* __restrict__ feat2,
        float* __restrict__ out) {
    int idx = blockIdx.x * blockDim.x + threadIdx.x;
    int total = NB * H0 * W0;
    if (idx >= total) return;
    int X = idx % W0;
    int Y = (idx / W0) % H0;
    int b = idx / (W0 * H0);

    const float* feats[2] = {feat1, feat2};
    const int dims[2] = {128, 32};
    const int choffs[2] = {17, 34};

    #pragma unroll
    for (int l = 0; l < 2; l++) {
        int h = dims[l], w = dims[l];
        float sy = (float)(h - 1) / (float)(H0 - 1);
        float sx = (float)(w - 1) / (float)(W0 - 1);
        float yf = (float)Y * sy;
        float xf = (float)X * sx;
        int y0 = (int)yf;
        int x0 = (int)xf;
        if (y0 > h - 1) y0 = h - 1;
        if (x0 > w - 1) x0 = w - 1;
        int y1 = min(y0 + 1, h - 1);
        int x1 = min(x0 + 1, w - 1);
        float fy = yf - (float)y0;
        float fx = xf - (float)x0;

        const float* fb = feats[l] + (size_t)b * NCH * h * w;
        float* ob = out + ((size_t)b * OUTC + choffs[l]) * (size_t)(H0 * W0) + (size_t)Y * W0 + X;
        for (int c = 0; c < NCH; c++) {
            const float* fc = fb + (size_t)c * h * w;
            float v00 = fc[(size_t)y0 * w + x0];
            float v01 = fc[(size_t)y0 * w + x1];
            float v10 = fc[(size_t)y1 * w + x0];
            float v11 = fc[(size_t)y1 * w + x1];
            float a  = v00 * (1.f - fy) + v10 * fy;
            float bb = v01 * (1.f - fy) + v11 * fy;
            ob[(size_t)c * (H0 * W0)] = a * (1.f - fx) + bb * fx;
        }
    }
}

extern "C" void kernel_launch(void* const* d_in, const int* in_sizes, int n_in,
                              void* d_out, int out_size, void* d_ws, size_t ws_size,
                              hipStream_t stream) {
    const float* x = (const float*)d_in[0];
    float* out = (float*)d_out;
    float* ws = (float*)d_ws;

    // workspace layout (floats)
    float* pool1 = ws;                                            // 4*48*128*128
    float* pool2 = pool1 + (size_t)NB * NC * 128 * 128;           // 4*48*32*32
    float* feat1 = pool2 + (size_t)NB * NC * 32 * 32;             // 4*17*128*128
    float* feat2 = feat1 + (size_t)NB * NCH * 128 * 128;          // 4*17*32*32

    // level 0: features -> out ch 0..16 (cpb=51), pool -> pool1. x read once.
    {
        int blocks = NB * (512 / TW) * (512 / TH);   // 4096
        feat_pool_lds<true><<<blocks, 256, 0, stream>>>(x, out, pool1, 512, 512, OUTC);
    }
    // level 1: features -> feat1 (cpb=17), pool -> pool2
    {
        int blocks = NB * (128 / TW) * (128 / TH);   // 256
        feat_pool_lds<true><<<blocks, 256, 0, stream>>>(pool1, feat1, pool2, 128, 128, NCH);
    }
    // level 2: features only -> feat2
    {
        int t = NB * 32 * 32;
        feat_kernel<<<(t + 255) / 256, 256, 0, stream>>>(pool2, feat2, 32, 32);
    }
    // upsample both levels -> out ch 17..50
    {
        int t = NB * H0 * W0;
        upsample_both_kernel<<<(t + 255) / 256, 256, 0, stream>>>(feat1, feat2, out);
    }
}